// Round 7
// baseline (121.100 us; speedup 1.0000x reference)
//
#include <hip/hip_runtime.h>
#include <math.h>
#include <float.h>

#define DD   128
#define KX   65          // D/2+1
#define NB   4
#define NTT  2
#define NG   125
#define NBTG (NB*NTT*NG) // 1000
#define WIN  24
#define H0   52

// padded volume dims: z,y in [0,131] (interior at +1), x in [0,67]
#define PZ  132
#define PY  132
#define PX  68
#define PROW  PX            // 68
#define PPLANE (PY*PX)      // 8976

typedef float f4 __attribute__((ext_vector_type(4), aligned(8)));

__device__ __forceinline__ float2 cmul(float2 a, float2 b){
    return make_float2(a.x*b.x - a.y*b.y, a.x*b.y + a.y*b.x);
}

// inline twiddle table: sTw[m] = e^{+2*pi*i*m/128}
__device__ __forceinline__ void make_tw(float2* sTw, int tid){
    if (tid < 128){
        float s, c;
        sincosf((float)tid * (float)(M_PI/64.0), &s, &c);
        sTw[tid] = make_float2(c, s);
    }
}

// Stage A (fused): bid<512 -> vol rfft-x via 2-real-rows-as-complex +
// radix-4 x2 levels + 8-term dots + Hermitian unpack;
// bid>=512 -> image rfft-x (direct).
__global__ __launch_bounds__(256) void k_stageA(const float* __restrict__ vol,
                       const float* __restrict__ imgs,
                       float2* __restrict__ A1, float2* __restrict__ B1){
    __shared__ float2 sZ [16*DD];   // 16 KB
    __shared__ float2 sZ2[16*DD];   // 16 KB
    __shared__ float2 sTw[128];
    int tid = threadIdx.x;
    int bid = blockIdx.x;
    make_tw(sTw, tid);
    __syncthreads();

    if (bid < 512){
        int z = bid >> 2, q = bid & 3;
        int y0 = q*32;
        float fz = (z-64)*(1.0f/128.0f);
        for (int i = tid; i < 16*DD; i += 256){
            int p = i >> 7, x = i & 127;
            int yA = y0 + 2*p;
            float fx = (x-64)*(1.0f/128.0f);
            float fyA = (yA-64)*(1.0f/128.0f);
            float fyB = fyA + (1.0f/128.0f);
            float b2 = fz*fz + fx*fx;
            float rA = sqrtf(b2 + fyA*fyA);
            float rB = sqrtf(b2 + fyB*fyB);
            float sA = (rA > 0.f) ? (sinf((float)M_PI*rA)/((float)M_PI*rA)) : 1.f;
            float sB = (rB > 0.f) ? (sinf((float)M_PI*rB)/((float)M_PI*rB)) : 1.f;
            float a = vol[(z*DD + yA)*DD + x] * sA * sA;
            float b = vol[(z*DD + yA+1)*DD + x] * sB * sB;
            sZ[i] = make_float2(a, b);
        }
        __syncthreads();
        // level 1 (forward)
        for (int i = tid; i < 16*32; i += 256){
            int p = i >> 5, x1 = i & 31;
            int b0 = p*DD + x1;
            float2 a = sZ[b0], bb = sZ[b0+32], c2 = sZ[b0+64], d = sZ[b0+96];
            float acx=a.x+c2.x, acy=a.y+c2.y;
            float amx=a.x-c2.x, amy=a.y-c2.y;
            float bdx=bb.x+d.x, bdy=bb.y+d.y;
            float bmx=bb.x-d.x, bmy=bb.y-d.y;
            sZ[b0   ] = make_float2(acx+bdx, acy+bdy);     // c=0
            sZ[b0+32] = make_float2(amx+bmy, amy-bmx);     // c=1: (a-c2)-i(b-d)
            sZ[b0+64] = make_float2(acx-bdx, acy-bdy);     // c=2
            sZ[b0+96] = make_float2(amx-bmy, amy+bmx);     // c=3: +i(b-d)
        }
        __syncthreads();
        // level 2 (forward, in place)
        for (int i = tid; i < 16*32; i += 256){
            int p = i >> 5, r5 = i & 31;
            int c = r5 >> 3, x2 = r5 & 7;
            int b0 = p*DD + 32*c + x2;
            float2 u0 = sZ[b0], u1 = sZ[b0+8], u2 = sZ[b0+16], u3 = sZ[b0+24];
            float2 w1 = sTw[(8*c)&127];  w1.y = -w1.y;
            float2 w2 = sTw[(16*c)&127]; w2.y = -w2.y;
            float2 w3 = sTw[(24*c)&127]; w3.y = -w3.y;
            float2 t1 = cmul(u1,w1), t2 = cmul(u2,w2), t3 = cmul(u3,w3);
            float2 pp = make_float2(u0.x+t2.x, u0.y+t2.y);
            float2 qq = make_float2(u0.x-t2.x, u0.y-t2.y);
            float2 rr = make_float2(t1.x+t3.x, t1.y+t3.y);
            float2 ss = make_float2(t1.x-t3.x, t1.y-t3.y);
            sZ[b0   ] = make_float2(pp.x+rr.x, pp.y+rr.y);   // s=0
            sZ[b0+8 ] = make_float2(qq.x+ss.y, qq.y-ss.x);   // s=1: q - i s
            sZ[b0+16] = make_float2(pp.x-rr.x, pp.y-rr.y);   // s=2
            sZ[b0+24] = make_float2(qq.x-ss.y, qq.y+ss.x);   // s=3: q + i s
        }
        __syncthreads();
        // 8-term dots
        for (int i = tid; i < 16*DD; i += 256){
            int p = i >> 7, k = i & 127;
            int c = k & 3, s = (k >> 2) & 3;
            const float2* v = &sZ[p*DD + 32*c + 8*s];
            float ar0=0,ai0=0,ar1=0,ai1=0;
            int j = 0;
            #pragma unroll
            for (int x2 = 0; x2 < 8; x2 += 2){
                float2 v0 = v[x2], v1 = v[x2+1];
                float2 e0 = sTw[j]; int jn = (j + k)&127;
                float2 e1 = sTw[jn];
                ar0 += v0.x*e0.x + v0.y*e0.y;  ai0 += v0.y*e0.x - v0.x*e0.y;
                ar1 += v1.x*e1.x + v1.y*e1.y;  ai1 += v1.y*e1.x - v1.x*e1.y;
                j = (jn + k)&127;
            }
            sZ2[i] = make_float2(ar0+ar1, ai0+ai1);
        }
        __syncthreads();
        // Hermitian unpack
        for (int i = tid; i < 16*KX; i += 256){
            int p = i / KX, k = i - p*KX;
            float2 Zk = sZ2[p*DD + k];
            float2 Zm = sZ2[p*DD + ((128-k)&127)];
            float2 A = make_float2(0.5f*(Zk.x+Zm.x), 0.5f*(Zk.y-Zm.y));
            float Dx = Zk.x - Zm.x, Dy = Zk.y + Zm.y;
            float2 Bv = make_float2(0.5f*Dy, -0.5f*Dx);
            int yA = y0 + 2*p;
            A1[(z*DD + yA  )*KX + k] = A;
            A1[(z*DD + yA+1)*KX + k] = Bv;
        }
    } else {
        int o = (bid - 512)*256 + tid;
        if (o >= NB*DD*KX) return;
        int b = o / (DD*KX);
        int r = o - b*DD*KX;
        int y = r / KX, k = r - y*KX;
        const float* row = imgs + (b*DD + y)*DD;
        float ar0=0,ai0=0,ar1=0,ai1=0,ar2=0,ai2=0,ar3=0,ai3=0;
        int i0=0, i1=k&127, i2=(2*k)&127, i3=(3*k)&127;
        int st = (4*k)&127;
        for (int x = 0; x < DD; x += 4){
            float v0=row[x], v1=row[x+1], v2=row[x+2], v3=row[x+3];
            float2 e0=sTw[i0], e1=sTw[i1], e2=sTw[i2], e3=sTw[i3];
            ar0 += v0*e0.x; ai0 -= v0*e0.y;
            ar1 += v1*e1.x; ai1 -= v1*e1.y;
            ar2 += v2*e2.x; ai2 -= v2*e2.y;
            ar3 += v3*e3.x; ai3 -= v3*e3.y;
            i0=(i0+st)&127; i1=(i1+st)&127; i2=(i2+st)&127; i3=(i3+st)&127;
        }
        B1[o] = make_float2(ar0+ar1+ar2+ar3, ai0+ai1+ai2+ai3);
    }
}

// Stage B (fused): bid<512 -> vol fft-y radix-4 x2 levels (class per block);
//                  bid>=512 -> image fft-y + signs + ctf premul -> Fc.
__global__ __launch_bounds__(256) void k_stageB(const float2* __restrict__ A1,
                       const float* __restrict__ ctf, const float2* __restrict__ B1,
                       float2* __restrict__ A2, float2* __restrict__ Fc){
    __shared__ float2 sU[32*KX];   // 16640 B
    __shared__ float2 sTw[128];
    int tid = threadIdx.x;
    int bid = blockIdx.x;
    make_tw(sTw, tid);
    __syncthreads();

    if (bid < 512){
        int z = bid >> 2, c = bid & 3;
        const float2* base = A1 + z*DD*KX;
        for (int i = tid; i < 32*KX; i += 256){
            int n = i / KX, kk = i - n*KX;
            float2 a  = base[(n    )*KX + kk];
            float2 bb = base[(n+32)*KX + kk];
            float2 c2 = base[(n+64)*KX + kk];
            float2 d  = base[(n+96)*KX + kk];
            float acx = a.x + c2.x, acy = a.y + c2.y;
            float amx = a.x - c2.x, amy = a.y - c2.y;
            float bdx = bb.x + d.x, bdy = bb.y + d.y;
            float bmx = bb.x - d.x, bmy = bb.y - d.y;
            float2 u;
            if (c == 0)      u = make_float2(acx + bdx, acy + bdy);
            else if (c == 2) u = make_float2(acx - bdx, acy - bdy);
            else if (c == 1) u = make_float2(amx + bmy, amy - bmx);   // (a-c2) - i(b-d)
            else             u = make_float2(amx - bmy, amy + bmx);   // (a-c2) + i(b-d)
            sU[i] = u;
        }
        __syncthreads();
        float2 w1 = sTw[(8*c)&127];  w1.y = -w1.y;
        float2 w2 = sTw[(16*c)&127]; w2.y = -w2.y;
        float2 w3 = sTw[(24*c)&127]; w3.y = -w3.y;
        for (int i = tid; i < 8*KX; i += 256){
            int n2 = i / KX, kk = i - n2*KX;
            int b0 = n2*KX + kk;
            float2 u0 = sU[b0], u1 = sU[b0+8*KX], u2 = sU[b0+16*KX], u3 = sU[b0+24*KX];
            float2 t1 = cmul(u1,w1), t2 = cmul(u2,w2), t3 = cmul(u3,w3);
            float2 p = make_float2(u0.x+t2.x, u0.y+t2.y);
            float2 q = make_float2(u0.x-t2.x, u0.y-t2.y);
            float2 r = make_float2(t1.x+t3.x, t1.y+t3.y);
            float2 s = make_float2(t1.x-t3.x, t1.y-t3.y);
            sU[b0       ] = make_float2(p.x+r.x, p.y+r.y);   // s=0
            sU[b0+ 8*KX ] = make_float2(q.x+s.y, q.y-s.x);   // s=1: q - i s
            sU[b0+16*KX ] = make_float2(p.x-r.x, p.y-r.y);   // s=2
            sU[b0+24*KX ] = make_float2(q.x-s.y, q.y+s.x);   // s=3: q + i s
        }
        __syncthreads();
        for (int o = tid; o < 32*KX; o += 256){
            int m = o / KX, kk = o - m*KX;
            int ky = 4*m + c;
            int s4 = m & 3;
            const float2* v = &sU[(8*s4)*KX + kk];
            float ar0=0,ai0=0,ar1=0,ai1=0;
            int j = 0;
            #pragma unroll
            for (int n2 = 0; n2 < 8; n2 += 2){
                float2 v0 = v[n2*KX], v1 = v[(n2+1)*KX];
                float2 e0 = sTw[j]; int jn = (j + ky)&127;
                float2 e1 = sTw[jn];
                ar0 += v0.x*e0.x + v0.y*e0.y;  ai0 += v0.y*e0.x - v0.x*e0.y;
                ar1 += v1.x*e1.x + v1.y*e1.y;  ai1 += v1.y*e1.x - v1.x*e1.y;
                j = (jn + ky)&127;
            }
            A2[(z*DD + ky)*KX + kk] = make_float2(ar0+ar1, ai0+ai1);
        }
    } else {
        int o = (bid - 512)*256 + tid;
        if (o >= NB*DD*KX) return;
        int b = o / (DD*KX);
        int r = o - b*DD*KX;
        int h = r / KX, k = r - h*KX;
        int kky = (h + 64) & 127;
        const float2* col = B1 + b*DD*KX + k;
        float ar0=0,ai0=0,ar1=0,ai1=0,ar2=0,ai2=0,ar3=0,ai3=0;
        int i0=0, i1=kky&127, i2=(2*kky)&127, i3=(3*kky)&127;
        int st = (4*kky)&127;
        for (int y = 0; y < DD; y += 4){
            float2 v0=col[(y+0)*KX], v1=col[(y+1)*KX];
            float2 v2=col[(y+2)*KX], v3=col[(y+3)*KX];
            float2 e0=sTw[i0], e1=sTw[i1], e2=sTw[i2], e3=sTw[i3];
            ar0 += v0.x*e0.x + v0.y*e0.y;  ai0 += v0.y*e0.x - v0.x*e0.y;
            ar1 += v1.x*e1.x + v1.y*e1.y;  ai1 += v1.y*e1.x - v1.x*e1.y;
            ar2 += v2.x*e2.x + v2.y*e2.y;  ai2 += v2.y*e2.x - v2.x*e2.y;
            ar3 += v3.x*e3.x + v3.y*e3.y;  ai3 += v3.y*e3.x - v3.x*e3.y;
            i0=(i0+st)&127; i1=(i1+st)&127; i2=(i2+st)&127; i3=(i3+st)&127;
        }
        float sgn = ((h + k)&1) ? -1.f : 1.f;
        float cf = ctf[o];
        Fc[o] = make_float2((ar0+ar1+ar2+ar3)*sgn*cf, (ai0+ai1+ai2+ai3)*sgn*cf);
    }
}

// Stage D: fft along z (radix-4 x2) + (-1)^{hz+hy+k} + fftshift store into
// the zero-halo padded volume VrP at (+1,+1,+0).
__global__ __launch_bounds__(256) void k_volD(const float2* __restrict__ A2,
                       float2* __restrict__ VrP){
    __shared__ float2 sU[32*KX];
    __shared__ float2 sTw[128];
    int tid = threadIdx.x;
    int bid = blockIdx.x;
    int ky = bid >> 2, c = bid & 3;
    make_tw(sTw, tid);
    __syncthreads();
    const float2* base = A2 + ky*KX;
    for (int i = tid; i < 32*KX; i += 256){
        int n = i / KX, kk = i - n*KX;
        float2 a  = base[(n    )*DD*KX + kk];
        float2 bb = base[(n+32)*DD*KX + kk];
        float2 c2 = base[(n+64)*DD*KX + kk];
        float2 d  = base[(n+96)*DD*KX + kk];
        float acx = a.x + c2.x, acy = a.y + c2.y;
        float amx = a.x - c2.x, amy = a.y - c2.y;
        float bdx = bb.x + d.x, bdy = bb.y + d.y;
        float bmx = bb.x - d.x, bmy = bb.y - d.y;
        float2 u;
        if (c == 0)      u = make_float2(acx + bdx, acy + bdy);
        else if (c == 2) u = make_float2(acx - bdx, acy - bdy);
        else if (c == 1) u = make_float2(amx + bmy, amy - bmx);
        else             u = make_float2(amx - bmy, amy + bmx);
        sU[i] = u;
    }
    __syncthreads();
    float2 w1 = sTw[(8*c)&127];  w1.y = -w1.y;
    float2 w2 = sTw[(16*c)&127]; w2.y = -w2.y;
    float2 w3 = sTw[(24*c)&127]; w3.y = -w3.y;
    for (int i = tid; i < 8*KX; i += 256){
        int n2 = i / KX, kk = i - n2*KX;
        int b0 = n2*KX + kk;
        float2 u0 = sU[b0], u1 = sU[b0+8*KX], u2 = sU[b0+16*KX], u3 = sU[b0+24*KX];
        float2 t1 = cmul(u1,w1), t2 = cmul(u2,w2), t3 = cmul(u3,w3);
        float2 p = make_float2(u0.x+t2.x, u0.y+t2.y);
        float2 q = make_float2(u0.x-t2.x, u0.y-t2.y);
        float2 r = make_float2(t1.x+t3.x, t1.y+t3.y);
        float2 s = make_float2(t1.x-t3.x, t1.y-t3.y);
        sU[b0       ] = make_float2(p.x+r.x, p.y+r.y);
        sU[b0+ 8*KX ] = make_float2(q.x+s.y, q.y-s.x);
        sU[b0+16*KX ] = make_float2(p.x-r.x, p.y-r.y);
        sU[b0+24*KX ] = make_float2(q.x-s.y, q.y+s.x);
    }
    __syncthreads();
    int hy = (ky + 64) & 127;
    for (int o = tid; o < 32*KX; o += 256){
        int m = o / KX, kk = o - m*KX;
        int kz = 4*m + c;
        int hz = (kz + 64) & 127;
        int s4 = m & 3;
        const float2* v = &sU[(8*s4)*KX + kk];
        float ar0=0,ai0=0,ar1=0,ai1=0;
        int j = 0;
        #pragma unroll
        for (int n2 = 0; n2 < 8; n2 += 2){
            float2 v0 = v[n2*KX], v1 = v[(n2+1)*KX];
            float2 e0 = sTw[j]; int jn = (j + kz)&127;
            float2 e1 = sTw[jn];
            ar0 += v0.x*e0.x + v0.y*e0.y;  ai0 += v0.y*e0.x - v0.x*e0.y;
            ar1 += v1.x*e1.x + v1.y*e1.y;  ai1 += v1.y*e1.x - v1.x*e1.y;
            j = (jn + kz)&127;
        }
        float sgn = ((hz + hy + kk) & 1) ? -1.f : 1.f;
        VrP[((hz+1)*PY + (hy+1))*PX + kk] = make_float2((ar0+ar1)*sgn, (ai0+ai1)*sgn);
    }
}

// Main: per (b,t,g): k in 4 chunks (17,17,17,14); per chunk:
// slice-extract*Fc (branchless, zero-halo padded gather) -> radix-4 level1 ->
// level2 -> 8-term y-IDFT rows. Then Hermitian-folded x-irfft -> wave argmax.
__global__ __launch_bounds__(256,4) void k_main(
    const float2* __restrict__ VrP, const float2* __restrict__ Fc,
    const float* __restrict__ rotm, const float* __restrict__ grid,
    float* __restrict__ resVal, int2* __restrict__ resShift)
{
    __shared__ float2 sP[DD*17];      // 17408 B
    __shared__ float2 sT[WIN*KX];     // 12480 B
    __shared__ float2 sTw[128];       // 1024 B
    __shared__ float  sM[9];
    __shared__ float  swv[4];
    __shared__ int    swi[4];

    int tid = threadIdx.x;
    int blk = blockIdx.x;
    int b  = blk / (NTT*NG);
    int rr = blk - b*NTT*NG;
    int t  = rr / NG;
    int g  = rr - t*NG;

    make_tw(sTw, tid);
    if (tid < 9){
        int i = tid/3, k = tid - 3*i;
        const float* R  = rotm + (b*NTT + t)*9;
        const float* Gm = grid + g*9;
        sM[tid] = R[i*3+0]*Gm[0*3+k] + R[i*3+1]*Gm[1*3+k] + R[i*3+2]*Gm[2*3+k];
    }
    __syncthreads();

    float M00=sM[0], M01=sM[1], M10=sM[3], M11=sM[4], M20=sM[6], M21=sM[7];
    const float2* FcB = Fc + b*DD*KX;

    const int KB[4]  = {0,17,34,51};
    const int NKc[4] = {17,17,17,14};
    #pragma unroll
    for (int cc = 0; cc < 4; ++cc){
        const int kbase = KB[cc];
        const int Nk    = NKc[cc];

        // Phase 1: central slice (trilinear via zero-halo, conj-flip), * Fc, conj
        #pragma unroll 2
        for (int idx = tid; idx < DD*Nk; idx += 256){
            int h = idx / Nk, kk = idx - h*Nk;
            int w = kbase + kk;
            float hf = (float)(h - 64);
            float wf = (float)w;
            float xi = M01*hf + M00*wf;           // rx*128
            float zi = M21*hf + M20*wf + 64.f;
            float yi = M11*hf + M10*wf + 64.f;
            bool neg = xi < 0.f;
            if (neg){ xi = -xi; zi = 128.f - zi; yi = 128.f - yi; }
            // clamps reproduce reference zero/partial-weight boundary behavior
            xi = fminf(xi, 65.f);
            zi = fminf(fmaxf(zi, -1.f), 129.f);
            yi = fminf(fmaxf(yi, -1.f), 129.f);
            float z0f = floorf(zi), y0f = floorf(yi), x0f = floorf(xi);
            float fz2 = zi - z0f, fy2 = yi - y0f, fx2 = xi - x0f;
            int z0 = (int)z0f, y0 = (int)y0f, x0 = (int)x0f;
            int basei = ((z0+1)*PY + (y0+1))*PX + x0;
            f4 v00 = *reinterpret_cast<const f4*>(VrP + basei);
            f4 v01 = *reinterpret_cast<const f4*>(VrP + basei + PROW);
            f4 v10 = *reinterpret_cast<const f4*>(VrP + basei + PPLANE);
            f4 v11 = *reinterpret_cast<const f4*>(VrP + basei + PPLANE + PROW);
            float2 f = FcB[h*KX + w];
            float gx = 1.f - fx2;
            float r00 = v00.x*gx + v00.z*fx2, i00 = v00.y*gx + v00.w*fx2;
            float r01 = v01.x*gx + v01.z*fx2, i01 = v01.y*gx + v01.w*fx2;
            float r10 = v10.x*gx + v10.z*fx2, i10 = v10.y*gx + v10.w*fx2;
            float r11 = v11.x*gx + v11.z*fx2, i11 = v11.y*gx + v11.w*fx2;
            float gz = 1.f - fz2, gy = 1.f - fy2;
            float w00 = gz*gy, w01 = gz*fy2, w10 = fz2*gy, w11 = fz2*fy2;
            float sr = r00*w00 + r01*w01 + r10*w10 + r11*w11;
            float si = i00*w00 + i01*w01 + i10*w10 + i11*w11;
            if (neg) si = -si;
            sP[h*17 + kk] = make_float2(f.x*sr + f.y*si, f.y*sr - f.x*si);
        }
        __syncthreads();

        // Level 1 (inverse: u_c = a + i^c b + (-1)^c c2 + (-i)^c d), rows 32c+n
        for (int i = tid; i < 32*Nk; i += 256){
            int n = i / Nk, kk = i - n*Nk;
            int o0 = n*17 + kk;
            float2 a  = sP[o0];
            float2 bb = sP[o0 + 32*17];
            float2 c2 = sP[o0 + 64*17];
            float2 d  = sP[o0 + 96*17];
            float acx = a.x + c2.x, acy = a.y + c2.y;
            float amx = a.x - c2.x, amy = a.y - c2.y;
            float bdx = bb.x + d.x, bdy = bb.y + d.y;
            float bmx = bb.x - d.x, bmy = bb.y - d.y;
            sP[o0        ] = make_float2(acx + bdx, acy + bdy);   // c=0
            sP[o0 + 32*17] = make_float2(amx - bmy, amy + bmx);   // c=1: + i(b-d)
            sP[o0 + 64*17] = make_float2(acx - bdx, acy - bdy);   // c=2
            sP[o0 + 96*17] = make_float2(amx + bmy, amy - bmx);   // c=3: - i(b-d)
        }
        __syncthreads();

        // Level 2 in place (inverse): v_s[n2] = sum_j u[n2+8j] w^{cj} i^{sj}
        for (int i = tid; i < 32*Nk; i += 256){
            int q = i / Nk, kk = i - q*Nk;
            int c = q >> 3, n2 = q & 7;
            int b0 = (32*c + n2)*17 + kk;
            float2 u0 = sP[b0], u1 = sP[b0+8*17], u2 = sP[b0+16*17], u3 = sP[b0+24*17];
            float2 w1 = sTw[(8*c)&127], w2 = sTw[(16*c)&127], w3 = sTw[(24*c)&127];
            float2 t1 = cmul(u1,w1), t2 = cmul(u2,w2), t3 = cmul(u3,w3);
            float2 p  = make_float2(u0.x+t2.x, u0.y+t2.y);
            float2 qq = make_float2(u0.x-t2.x, u0.y-t2.y);
            float2 r  = make_float2(t1.x+t3.x, t1.y+t3.y);
            float2 s  = make_float2(t1.x-t3.x, t1.y-t3.y);
            sP[b0       ] = make_float2(p.x+r.x,  p.y+r.y);    // s=0
            sP[b0+ 8*17 ] = make_float2(qq.x-s.y, qq.y+s.x);   // s=1: q + i s
            sP[b0+16*17 ] = make_float2(p.x-r.x,  p.y-r.y);    // s=2
            sP[b0+24*17 ] = make_float2(qq.x+s.y, qq.y-s.x);   // s=3: q - i s
        }
        __syncthreads();

        // Phase 2: 8-term y-IDFT per needed row
        for (int o = tid; o < WIN*Nk; o += 256){
            int a = o / Nk, kk = o - a*Nk;
            int ry = (116 + a) & 127;
            int c = ry & 3, s4 = (ry >> 2) & 3;
            const float2* v = &sP[(32*c + 8*s4)*17 + kk];
            float ar0=0,ai0=0,ar1=0,ai1=0;
            int j = 0;
            #pragma unroll
            for (int n2 = 0; n2 < 8; n2 += 2){
                float2 v0 = v[n2*17], v1 = v[(n2+1)*17];
                float2 e0 = sTw[j]; int jn = (j + ry)&127;
                float2 e1 = sTw[jn];
                ar0 += v0.x*e0.x - v0.y*e0.y;  ai0 += v0.x*e0.y + v0.y*e0.x;
                ar1 += v1.x*e1.x - v1.y*e1.y;  ai1 += v1.x*e1.y + v1.y*e1.x;
                j = (jn + ry)&127;
            }
            float sgn = (a & 1) ? -(1.f/128.f) : (1.f/128.f);   // (-1)^ry / 128
            sT[a*KX + kbase + kk] = make_float2((ar0+ar1)*sgn, (ai0+ai1)*sgn);
        }
        __syncthreads();
    }

    // Phase 3a: Hermitian fold into sP (free): Ae (even rx) / Ao (odd rx)
    float2* sPf = sP;
    for (int o = tid; o < WIN*31; o += 256){
        int a = o / 31, km1 = o - a*31;
        int k = km1 + 1;
        const float2* Trow = &sT[a*KX];
        float2 T1 = Trow[k], T2 = Trow[64-k];
        sPf[a*31 + km1]       = make_float2(T1.x + T2.x, T1.y - T2.y);
        sPf[744 + a*31 + km1] = make_float2(T1.x - T2.x, T1.y + T2.y);
    }
    __syncthreads();

    // Phase 3b: 31-term folded x-irfft on the 24x24 window
    float* sC = reinterpret_cast<float*>(sP + 1488);
    for (int o = tid; o < WIN*WIN; o += 256){
        int a = o / WIN, bx = o - a*WIN;
        int rx = (116 + bx) & 127;
        const float2* Trow = &sT[a*KX];
        float2 T32 = Trow[32];
        float base = Trow[0].x + ((bx & 1) ? -Trow[64].x : Trow[64].x);
        int r4 = rx & 3;
        base += (r4==0) ?  2.f*T32.x : (r4==1) ? -2.f*T32.y
              : (r4==2) ? -2.f*T32.x :  2.f*T32.y;
        const float2* A = sPf + ((bx & 1) ? 744 : 0) + a*31 - 1;  // A[k], k=1..31
        float acc0=0.f, acc1=0.f;
        int j1 = rx, j2 = (2*rx)&127;
        int st = (2*rx)&127;
        for (int k = 1; k < 31; k += 2){
            float2 e1 = sTw[j1]; float2 A1v = A[k];
            float2 e2 = sTw[j2]; float2 A2v = A[k+1];
            acc0 += A1v.x*e1.x - A1v.y*e1.y;
            acc1 += A2v.x*e2.x - A2v.y*e2.y;
            j1=(j1+st)&127; j2=(j2+st)&127;
        }
        {
            float2 e = sTw[(31*rx)&127]; float2 Av = A[31];
            acc0 += Av.x*e.x - Av.y*e.y;
        }
        sC[o] = (base + 2.f*(acc0+acc1))*(1.f/128.f);
    }
    __syncthreads();

    // Phase 4: argmax, row-major first occurrence — wave-level shfl_xor reduce
    float best = -FLT_MAX; int bidx = 0x7fffffff;
    for (int i = tid; i < WIN*WIN; i += 256){
        float v = sC[i];
        if (v > best){ best = v; bidx = i; }
    }
    #pragma unroll
    for (int s = 32; s > 0; s >>= 1){
        float ov = __shfl_xor(best, s, 64);
        int   oi = __shfl_xor(bidx, s, 64);
        if (ov > best || (ov == best && oi < bidx)){ best = ov; bidx = oi; }
    }
    if ((tid & 63) == 0){ swv[tid>>6] = best; swi[tid>>6] = bidx; }
    __syncthreads();
    if (tid == 0){
        float bv = swv[0]; int bi = swi[0];
        #pragma unroll
        for (int w2 = 1; w2 < 4; ++w2){
            if (swv[w2] > bv || (swv[w2] == bv && swi[w2] < bi)){ bv = swv[w2]; bi = swi[w2]; }
        }
        int a = bi / WIN, bx = bi - a*WIN;
        resVal[blk] = bv;
        resShift[blk] = make_int2(H0 + bx, H0 + a);
    }
}

// Final: per-batch top-2 (stable ties), mean/std(ddof=1), erf — parallel.
__global__ __launch_bounds__(256) void k_final(const float* __restrict__ resVal,
                        const int2* __restrict__ resShift,
                        const float* __restrict__ grid, float* __restrict__ out)
{
    __shared__ float sv[256];
    __shared__ int   si[256];
    __shared__ float sr[256];
    __shared__ float sMean;
    const int N = NTT*NG;   // 250
    int b = blockIdx.x, tid = threadIdx.x;
    const float* v = resVal + b*N;
    float myv = (tid < N) ? v[tid] : -FLT_MAX;

    sv[tid] = myv; si[tid] = (tid < N) ? tid : 0x7fffffff;
    __syncthreads();
    for (int s = 128; s > 0; s >>= 1){
        if (tid < s){
            float v2 = sv[tid+s]; int i2 = si[tid+s];
            if (v2 > sv[tid] || (v2 == sv[tid] && i2 < si[tid])){ sv[tid]=v2; si[tid]=i2; }
        }
        __syncthreads();
    }
    float v0 = sv[0]; int i0 = si[0];
    __syncthreads();

    bool act = (tid < N) && (tid != i0);
    sv[tid] = act ? myv : -FLT_MAX; si[tid] = act ? tid : 0x7fffffff;
    __syncthreads();
    for (int s = 128; s > 0; s >>= 1){
        if (tid < s){
            float v2 = sv[tid+s]; int i2 = si[tid+s];
            if (v2 > sv[tid] || (v2 == sv[tid] && i2 < si[tid])){ sv[tid]=v2; si[tid]=i2; }
        }
        __syncthreads();
    }
    float v1 = sv[0]; int i1 = si[0];
    __syncthreads();

    sr[tid] = (tid < N) ? myv : 0.f;
    __syncthreads();
    for (int s = 128; s > 0; s >>= 1){
        if (tid < s) sr[tid] += sr[tid+s];
        __syncthreads();
    }
    if (tid == 0) sMean = sr[0] / (float)N;
    __syncthreads();
    float mean = sMean;

    float d = (tid < N) ? (myv - mean) : 0.f;
    sr[tid] = d*d;
    __syncthreads();
    for (int s = 128; s > 0; s >>= 1){
        if (tid < s) sr[tid] += sr[tid+s];
        __syncthreads();
    }

    if (tid == 0){
        float stdv = sqrtf(sr[0] / (float)(N - 1));
        float vals[2] = {v0, v1};
        int   idxs[2] = {i0, i1};
        for (int k = 0; k < 2; ++k){
            out[b*2 + k] = vals[k];
            int gi = idxs[k] % NG;
            for (int j = 0; j < 9; ++j) out[8 + (b*2+k)*9 + j] = grid[gi*9 + j];
            int2 sh = resShift[b*N + idxs[k]];
            out[80 + (b*2+k)*2 + 0] = -((float)sh.x - 64.f)*1.5f;
            out[80 + (b*2+k)*2 + 1] = -((float)sh.y - 64.f)*1.5f;
            out[96 + b*2 + k] = 0.5f*(1.f + erff((vals[k] - mean)/(stdv*1.41421356237309515f)));
        }
    }
}

extern "C" void kernel_launch(void* const* d_in, const int* in_sizes, int n_in,
                              void* d_out, int out_size, void* d_ws, size_t ws_size,
                              hipStream_t stream)
{
    const float* vol  = (const float*)d_in[0];
    const float* imgs = (const float*)d_in[1];
    const float* ctf  = (const float*)d_in[2];
    const float* rotm = (const float*)d_in[3];
    const float* grid = (const float*)d_in[4];
    float* out = (float*)d_out;

    const size_t A1_BYTES  = (size_t)DD*DD*KX*sizeof(float2);   // 8,519,680
    const size_t B1_BYTES  = (size_t)NB*DD*KX*sizeof(float2);   //   266,240
    const size_t VRP_BYTES = (size_t)PZ*PY*PX*sizeof(float2);   // 9,483,264

    char* ws = (char*)d_ws;
    // VrP aliases [A1 | B1 | pad] (dead by the time VrP is written)
    float2* A1  = (float2*)(ws);
    float2* B1  = (float2*)(ws + A1_BYTES);
    float2* VrP = (float2*)(ws);
    size_t off = VRP_BYTES;
    float2* A2 = (float2*)(ws + off); off += A1_BYTES;
    float2* Fc = (float2*)(ws + off); off += B1_BYTES;
    float* resVal = (float*)(ws + off); off += (size_t)NBTG*sizeof(float);
    int2* resShift = (int2*)(ws + off); off += (size_t)NBTG*sizeof(int2);

    k_stageA<<<642, 256, 0, stream>>>(vol, imgs, A1, B1);
    k_stageB<<<642, 256, 0, stream>>>(A1, ctf, B1, A2, Fc);
    hipMemsetAsync(VrP, 0, VRP_BYTES, stream);   // zero halo (A1/B1 dead now)
    k_volD  <<<512, 256, 0, stream>>>(A2, VrP);
    k_main  <<<NBTG,256, 0, stream>>>(VrP, Fc, rotm, grid, resVal, resShift);
    k_final <<<NB,  256, 0, stream>>>(resVal, resShift, grid, out);
}

// Round 8
// 119.158 us; speedup vs baseline: 1.0163x; 1.0163x over previous
//
#include <hip/hip_runtime.h>
#include <math.h>
#include <float.h>

#define DD   128
#define KX   65          // D/2+1
#define NB   4
#define NTT  2
#define NG   125
#define NBTG (NB*NTT*NG) // 1000
#define WIN  24
#define H0   52

// padded volume dims: z,y in [0,131] (interior at +1), x in [0,67]
#define PZ  132
#define PY  132
#define PX  68
#define PROW  PX            // 68
#define PPLANE (PY*PX)      // 8976
#define HALO_N 119872       // unwritten cells zeroed by k_volD epilogue

typedef float f4 __attribute__((ext_vector_type(4), aligned(8)));

__device__ __forceinline__ float2 cmul(float2 a, float2 b){
    return make_float2(a.x*b.x - a.y*b.y, a.x*b.y + a.y*b.x);
}

// inline twiddle table: sTw[m] = e^{+2*pi*i*m/128}
__device__ __forceinline__ void make_tw(float2* sTw, int tid){
    if (tid < 128){
        float s, c;
        sincosf((float)tid * (float)(M_PI/64.0), &s, &c);
        sTw[tid] = make_float2(c, s);
    }
}

// Stage A (fused): bid<512 -> vol rfft-x via 2-real-rows-as-complex +
// radix-4 x2 levels + 8-term dots + Hermitian unpack;
// bid>=512 -> image rfft-x (direct).
__global__ __launch_bounds__(256) void k_stageA(const float* __restrict__ vol,
                       const float* __restrict__ imgs,
                       float2* __restrict__ A1, float2* __restrict__ B1){
    __shared__ float2 sZ [16*DD];   // 16 KB
    __shared__ float2 sZ2[16*DD];   // 16 KB
    __shared__ float2 sTw[128];
    int tid = threadIdx.x;
    int bid = blockIdx.x;
    make_tw(sTw, tid);
    __syncthreads();

    if (bid < 512){
        int z = bid >> 2, q = bid & 3;
        int y0 = q*32;
        float fz = (z-64)*(1.0f/128.0f);
        for (int i = tid; i < 16*DD; i += 256){
            int p = i >> 7, x = i & 127;
            int yA = y0 + 2*p;
            float fx = (x-64)*(1.0f/128.0f);
            float fyA = (yA-64)*(1.0f/128.0f);
            float fyB = fyA + (1.0f/128.0f);
            float b2 = fz*fz + fx*fx;
            float rA = sqrtf(b2 + fyA*fyA);
            float rB = sqrtf(b2 + fyB*fyB);
            float sA = (rA > 0.f) ? (sinf((float)M_PI*rA)/((float)M_PI*rA)) : 1.f;
            float sB = (rB > 0.f) ? (sinf((float)M_PI*rB)/((float)M_PI*rB)) : 1.f;
            float a = vol[(z*DD + yA)*DD + x] * sA * sA;
            float b = vol[(z*DD + yA+1)*DD + x] * sB * sB;
            sZ[i] = make_float2(a, b);
        }
        __syncthreads();
        // level 1 (forward)
        for (int i = tid; i < 16*32; i += 256){
            int p = i >> 5, x1 = i & 31;
            int b0 = p*DD + x1;
            float2 a = sZ[b0], bb = sZ[b0+32], c2 = sZ[b0+64], d = sZ[b0+96];
            float acx=a.x+c2.x, acy=a.y+c2.y;
            float amx=a.x-c2.x, amy=a.y-c2.y;
            float bdx=bb.x+d.x, bdy=bb.y+d.y;
            float bmx=bb.x-d.x, bmy=bb.y-d.y;
            sZ[b0   ] = make_float2(acx+bdx, acy+bdy);     // c=0
            sZ[b0+32] = make_float2(amx+bmy, amy-bmx);     // c=1: (a-c2)-i(b-d)
            sZ[b0+64] = make_float2(acx-bdx, acy-bdy);     // c=2
            sZ[b0+96] = make_float2(amx-bmy, amy+bmx);     // c=3: +i(b-d)
        }
        __syncthreads();
        // level 2 (forward, in place)
        for (int i = tid; i < 16*32; i += 256){
            int p = i >> 5, r5 = i & 31;
            int c = r5 >> 3, x2 = r5 & 7;
            int b0 = p*DD + 32*c + x2;
            float2 u0 = sZ[b0], u1 = sZ[b0+8], u2 = sZ[b0+16], u3 = sZ[b0+24];
            float2 w1 = sTw[(8*c)&127];  w1.y = -w1.y;
            float2 w2 = sTw[(16*c)&127]; w2.y = -w2.y;
            float2 w3 = sTw[(24*c)&127]; w3.y = -w3.y;
            float2 t1 = cmul(u1,w1), t2 = cmul(u2,w2), t3 = cmul(u3,w3);
            float2 pp = make_float2(u0.x+t2.x, u0.y+t2.y);
            float2 qq = make_float2(u0.x-t2.x, u0.y-t2.y);
            float2 rr = make_float2(t1.x+t3.x, t1.y+t3.y);
            float2 ss = make_float2(t1.x-t3.x, t1.y-t3.y);
            sZ[b0   ] = make_float2(pp.x+rr.x, pp.y+rr.y);   // s=0
            sZ[b0+8 ] = make_float2(qq.x+ss.y, qq.y-ss.x);   // s=1: q - i s
            sZ[b0+16] = make_float2(pp.x-rr.x, pp.y-rr.y);   // s=2
            sZ[b0+24] = make_float2(qq.x-ss.y, qq.y+ss.x);   // s=3: q + i s
        }
        __syncthreads();
        // 8-term dots
        for (int i = tid; i < 16*DD; i += 256){
            int p = i >> 7, k = i & 127;
            int c = k & 3, s = (k >> 2) & 3;
            const float2* v = &sZ[p*DD + 32*c + 8*s];
            float ar0=0,ai0=0,ar1=0,ai1=0;
            int j = 0;
            #pragma unroll
            for (int x2 = 0; x2 < 8; x2 += 2){
                float2 v0 = v[x2], v1 = v[x2+1];
                float2 e0 = sTw[j]; int jn = (j + k)&127;
                float2 e1 = sTw[jn];
                ar0 += v0.x*e0.x + v0.y*e0.y;  ai0 += v0.y*e0.x - v0.x*e0.y;
                ar1 += v1.x*e1.x + v1.y*e1.y;  ai1 += v1.y*e1.x - v1.x*e1.y;
                j = (jn + k)&127;
            }
            sZ2[i] = make_float2(ar0+ar1, ai0+ai1);
        }
        __syncthreads();
        // Hermitian unpack
        for (int i = tid; i < 16*KX; i += 256){
            int p = i / KX, k = i - p*KX;
            float2 Zk = sZ2[p*DD + k];
            float2 Zm = sZ2[p*DD + ((128-k)&127)];
            float2 A = make_float2(0.5f*(Zk.x+Zm.x), 0.5f*(Zk.y-Zm.y));
            float Dx = Zk.x - Zm.x, Dy = Zk.y + Zm.y;
            float2 Bv = make_float2(0.5f*Dy, -0.5f*Dx);
            int yA = y0 + 2*p;
            A1[(z*DD + yA  )*KX + k] = A;
            A1[(z*DD + yA+1)*KX + k] = Bv;
        }
    } else {
        int o = (bid - 512)*256 + tid;
        if (o >= NB*DD*KX) return;
        int b = o / (DD*KX);
        int r = o - b*DD*KX;
        int y = r / KX, k = r - y*KX;
        const float* row = imgs + (b*DD + y)*DD;
        float ar0=0,ai0=0,ar1=0,ai1=0,ar2=0,ai2=0,ar3=0,ai3=0;
        int i0=0, i1=k&127, i2=(2*k)&127, i3=(3*k)&127;
        int st = (4*k)&127;
        for (int x = 0; x < DD; x += 4){
            float v0=row[x], v1=row[x+1], v2=row[x+2], v3=row[x+3];
            float2 e0=sTw[i0], e1=sTw[i1], e2=sTw[i2], e3=sTw[i3];
            ar0 += v0*e0.x; ai0 -= v0*e0.y;
            ar1 += v1*e1.x; ai1 -= v1*e1.y;
            ar2 += v2*e2.x; ai2 -= v2*e2.y;
            ar3 += v3*e3.x; ai3 -= v3*e3.y;
            i0=(i0+st)&127; i1=(i1+st)&127; i2=(i2+st)&127; i3=(i3+st)&127;
        }
        B1[o] = make_float2(ar0+ar1+ar2+ar3, ai0+ai1+ai2+ai3);
    }
}

// Stage B (fused): bid<512 -> vol fft-y radix-4 x2 levels (class per block);
//                  bid>=512 -> image fft-y + signs + ctf premul -> Fc.
__global__ __launch_bounds__(256) void k_stageB(const float2* __restrict__ A1,
                       const float* __restrict__ ctf, const float2* __restrict__ B1,
                       float2* __restrict__ A2, float2* __restrict__ Fc){
    __shared__ float2 sU[32*KX];   // 16640 B
    __shared__ float2 sTw[128];
    int tid = threadIdx.x;
    int bid = blockIdx.x;
    make_tw(sTw, tid);
    __syncthreads();

    if (bid < 512){
        int z = bid >> 2, c = bid & 3;
        const float2* base = A1 + z*DD*KX;
        for (int i = tid; i < 32*KX; i += 256){
            int n = i / KX, kk = i - n*KX;
            float2 a  = base[(n    )*KX + kk];
            float2 bb = base[(n+32)*KX + kk];
            float2 c2 = base[(n+64)*KX + kk];
            float2 d  = base[(n+96)*KX + kk];
            float acx = a.x + c2.x, acy = a.y + c2.y;
            float amx = a.x - c2.x, amy = a.y - c2.y;
            float bdx = bb.x + d.x, bdy = bb.y + d.y;
            float bmx = bb.x - d.x, bmy = bb.y - d.y;
            float2 u;
            if (c == 0)      u = make_float2(acx + bdx, acy + bdy);
            else if (c == 2) u = make_float2(acx - bdx, acy - bdy);
            else if (c == 1) u = make_float2(amx + bmy, amy - bmx);   // (a-c2) - i(b-d)
            else             u = make_float2(amx - bmy, amy + bmx);   // (a-c2) + i(b-d)
            sU[i] = u;
        }
        __syncthreads();
        float2 w1 = sTw[(8*c)&127];  w1.y = -w1.y;
        float2 w2 = sTw[(16*c)&127]; w2.y = -w2.y;
        float2 w3 = sTw[(24*c)&127]; w3.y = -w3.y;
        for (int i = tid; i < 8*KX; i += 256){
            int n2 = i / KX, kk = i - n2*KX;
            int b0 = n2*KX + kk;
            float2 u0 = sU[b0], u1 = sU[b0+8*KX], u2 = sU[b0+16*KX], u3 = sU[b0+24*KX];
            float2 t1 = cmul(u1,w1), t2 = cmul(u2,w2), t3 = cmul(u3,w3);
            float2 p = make_float2(u0.x+t2.x, u0.y+t2.y);
            float2 q = make_float2(u0.x-t2.x, u0.y-t2.y);
            float2 r = make_float2(t1.x+t3.x, t1.y+t3.y);
            float2 s = make_float2(t1.x-t3.x, t1.y-t3.y);
            sU[b0       ] = make_float2(p.x+r.x, p.y+r.y);   // s=0
            sU[b0+ 8*KX ] = make_float2(q.x+s.y, q.y-s.x);   // s=1: q - i s
            sU[b0+16*KX ] = make_float2(p.x-r.x, p.y-r.y);   // s=2
            sU[b0+24*KX ] = make_float2(q.x-s.y, q.y+s.x);   // s=3: q + i s
        }
        __syncthreads();
        for (int o = tid; o < 32*KX; o += 256){
            int m = o / KX, kk = o - m*KX;
            int ky = 4*m + c;
            int s4 = m & 3;
            const float2* v = &sU[(8*s4)*KX + kk];
            float ar0=0,ai0=0,ar1=0,ai1=0;
            int j = 0;
            #pragma unroll
            for (int n2 = 0; n2 < 8; n2 += 2){
                float2 v0 = v[n2*KX], v1 = v[(n2+1)*KX];
                float2 e0 = sTw[j]; int jn = (j + ky)&127;
                float2 e1 = sTw[jn];
                ar0 += v0.x*e0.x + v0.y*e0.y;  ai0 += v0.y*e0.x - v0.x*e0.y;
                ar1 += v1.x*e1.x + v1.y*e1.y;  ai1 += v1.y*e1.x - v1.x*e1.y;
                j = (jn + ky)&127;
            }
            A2[(z*DD + ky)*KX + kk] = make_float2(ar0+ar1, ai0+ai1);
        }
    } else {
        int o = (bid - 512)*256 + tid;
        if (o >= NB*DD*KX) return;
        int b = o / (DD*KX);
        int r = o - b*DD*KX;
        int h = r / KX, k = r - h*KX;
        int kky = (h + 64) & 127;
        const float2* col = B1 + b*DD*KX + k;
        float ar0=0,ai0=0,ar1=0,ai1=0,ar2=0,ai2=0,ar3=0,ai3=0;
        int i0=0, i1=kky&127, i2=(2*kky)&127, i3=(3*kky)&127;
        int st = (4*kky)&127;
        for (int y = 0; y < DD; y += 4){
            float2 v0=col[(y+0)*KX], v1=col[(y+1)*KX];
            float2 v2=col[(y+2)*KX], v3=col[(y+3)*KX];
            float2 e0=sTw[i0], e1=sTw[i1], e2=sTw[i2], e3=sTw[i3];
            ar0 += v0.x*e0.x + v0.y*e0.y;  ai0 += v0.y*e0.x - v0.x*e0.y;
            ar1 += v1.x*e1.x + v1.y*e1.y;  ai1 += v1.y*e1.x - v1.x*e1.y;
            ar2 += v2.x*e2.x + v2.y*e2.y;  ai2 += v2.y*e2.x - v2.x*e2.y;
            ar3 += v3.x*e3.x + v3.y*e3.y;  ai3 += v3.y*e3.x - v3.x*e3.y;
            i0=(i0+st)&127; i1=(i1+st)&127; i2=(i2+st)&127; i3=(i3+st)&127;
        }
        float sgn = ((h + k)&1) ? -1.f : 1.f;
        float cf = ctf[o];
        Fc[o] = make_float2((ar0+ar1+ar2+ar3)*sgn*cf, (ai0+ai1+ai2+ai3)*sgn*cf);
    }
}

// Stage D: fft along z (radix-4 x2) + (-1)^{hz+hy+k} + fftshift store into
// the zero-halo padded volume VrP at (+1,+1,+0); epilogue zeroes the halo.
__global__ __launch_bounds__(256) void k_volD(const float2* __restrict__ A2,
                       float2* __restrict__ VrP){
    __shared__ float2 sU[32*KX];
    __shared__ float2 sTw[128];
    int tid = threadIdx.x;
    int bid = blockIdx.x;
    int ky = bid >> 2, c = bid & 3;
    make_tw(sTw, tid);

    // halo zeroing (disjoint from interior stores; no sync needed)
    {
        int hidx = bid*234 + tid;   // 512*234 = 119808 < HALO_N... use 2 strides
        // cover HALO_N = 119872 with 512 blocks x 256 threads = 131072 slots
        hidx = bid*256 + tid;
        if (hidx < HALO_N){
            int z, y, x;
            if (hidx < 35904){                       // z in {0,129,130,131} full planes
                int p = hidx / 8976;
                int r = hidx - p*8976;
                z = (p == 0) ? 0 : (128 + p);
                y = r / 68;
                x = r - 68*y;
            } else if (hidx < 70720){                // z in [1,128], y in {0,129,130,131}
                int h2 = hidx - 35904;
                int zz = h2 / 272;
                int r = h2 - zz*272;
                z = 1 + zz;
                int p = r / 68;
                y = (p == 0) ? 0 : (128 + p);
                x = r - 68*p;
            } else {                                  // z,y interior, x in {65,66,67}
                int h3 = hidx - 70720;
                int zz = h3 / 384;
                int r = h3 - zz*384;
                z = 1 + zz;
                y = 1 + r/3;
                x = 65 + (r - 3*(r/3));
            }
            VrP[(z*PY + y)*PX + x] = make_float2(0.f, 0.f);
        }
    }
    __syncthreads();

    const float2* base = A2 + ky*KX;
    for (int i = tid; i < 32*KX; i += 256){
        int n = i / KX, kk = i - n*KX;
        float2 a  = base[(n    )*DD*KX + kk];
        float2 bb = base[(n+32)*DD*KX + kk];
        float2 c2 = base[(n+64)*DD*KX + kk];
        float2 d  = base[(n+96)*DD*KX + kk];
        float acx = a.x + c2.x, acy = a.y + c2.y;
        float amx = a.x - c2.x, amy = a.y - c2.y;
        float bdx = bb.x + d.x, bdy = bb.y + d.y;
        float bmx = bb.x - d.x, bmy = bb.y - d.y;
        float2 u;
        if (c == 0)      u = make_float2(acx + bdx, acy + bdy);
        else if (c == 2) u = make_float2(acx - bdx, acy - bdy);
        else if (c == 1) u = make_float2(amx + bmy, amy - bmx);
        else             u = make_float2(amx - bmy, amy + bmx);
        sU[i] = u;
    }
    __syncthreads();
    float2 w1 = sTw[(8*c)&127];  w1.y = -w1.y;
    float2 w2 = sTw[(16*c)&127]; w2.y = -w2.y;
    float2 w3 = sTw[(24*c)&127]; w3.y = -w3.y;
    for (int i = tid; i < 8*KX; i += 256){
        int n2 = i / KX, kk = i - n2*KX;
        int b0 = n2*KX + kk;
        float2 u0 = sU[b0], u1 = sU[b0+8*KX], u2 = sU[b0+16*KX], u3 = sU[b0+24*KX];
        float2 t1 = cmul(u1,w1), t2 = cmul(u2,w2), t3 = cmul(u3,w3);
        float2 p = make_float2(u0.x+t2.x, u0.y+t2.y);
        float2 q = make_float2(u0.x-t2.x, u0.y-t2.y);
        float2 r = make_float2(t1.x+t3.x, t1.y+t3.y);
        float2 s = make_float2(t1.x-t3.x, t1.y-t3.y);
        sU[b0       ] = make_float2(p.x+r.x, p.y+r.y);
        sU[b0+ 8*KX ] = make_float2(q.x+s.y, q.y-s.x);
        sU[b0+16*KX ] = make_float2(p.x-r.x, p.y-r.y);
        sU[b0+24*KX ] = make_float2(q.x-s.y, q.y+s.x);
    }
    __syncthreads();
    int hy = (ky + 64) & 127;
    for (int o = tid; o < 32*KX; o += 256){
        int m = o / KX, kk = o - m*KX;
        int kz = 4*m + c;
        int hz = (kz + 64) & 127;
        int s4 = m & 3;
        const float2* v = &sU[(8*s4)*KX + kk];
        float ar0=0,ai0=0,ar1=0,ai1=0;
        int j = 0;
        #pragma unroll
        for (int n2 = 0; n2 < 8; n2 += 2){
            float2 v0 = v[n2*KX], v1 = v[(n2+1)*KX];
            float2 e0 = sTw[j]; int jn = (j + kz)&127;
            float2 e1 = sTw[jn];
            ar0 += v0.x*e0.x + v0.y*e0.y;  ai0 += v0.y*e0.x - v0.x*e0.y;
            ar1 += v1.x*e1.x + v1.y*e1.y;  ai1 += v1.y*e1.x - v1.x*e1.y;
            j = (jn + kz)&127;
        }
        float sgn = ((hz + hy + kk) & 1) ? -1.f : 1.f;
        VrP[((hz+1)*PY + (hy+1))*PX + kk] = make_float2((ar0+ar1)*sgn, (ai0+ai1)*sgn);
    }
}

// Main: XCD-swizzled (each XCD gets one (b,t) x 125 g's for L2 locality).
// Per (b,t,g): k in 4 chunks; per chunk: 2-way-pipelined slice-extract*Fc ->
// radix-4 level1 -> level2 -> 8-term y-IDFT rows. Then folded x-irfft -> argmax.
__global__ __launch_bounds__(256,4) void k_main(
    const float2* __restrict__ VrP, const float2* __restrict__ Fc,
    const float* __restrict__ rotm, const float* __restrict__ grid,
    float* __restrict__ resVal, int2* __restrict__ resShift)
{
    __shared__ float2 sP[DD*17];      // 17408 B
    __shared__ float2 sT[WIN*KX];     // 12480 B
    __shared__ float2 sTw[128];       // 1024 B
    __shared__ float  sM[9];
    __shared__ float  swv[4];
    __shared__ int    swi[4];

    int tid = threadIdx.x;
    int nb  = blockIdx.x;
    // bijective XCD swizzle: XCD (nb&7) processes orig-blocks [(nb&7)*125, ...)
    int blk = (nb & 7)*125 + (nb >> 3);
    int b  = blk / (NTT*NG);
    int rr = blk - b*NTT*NG;
    int t  = rr / NG;
    int g  = rr - t*NG;

    make_tw(sTw, tid);
    if (tid < 9){
        int i = tid/3, k = tid - 3*i;
        const float* R  = rotm + (b*NTT + t)*9;
        const float* Gm = grid + g*9;
        sM[tid] = R[i*3+0]*Gm[0*3+k] + R[i*3+1]*Gm[1*3+k] + R[i*3+2]*Gm[2*3+k];
    }
    __syncthreads();

    float M00=sM[0], M01=sM[1], M10=sM[3], M11=sM[4], M20=sM[6], M21=sM[7];
    const float2* FcB = Fc + b*DD*KX;

    const int KB[4]  = {0,17,34,51};
    const int NKc[4] = {17,17,17,14};
    #pragma unroll
    for (int cc = 0; cc < 4; ++cc){
        const int kbase = KB[cc];
        const int Nk    = NKc[cc];
        const int total = DD*Nk;

        // Phase 1: 2-point pipelined slice-extract (zero-halo gather), *Fc, conj
        for (int base = 0; base < total; base += 512){
            int iA = base + tid;
            int iB = iA + 256;
            bool vA = iA < total, vB = iB < total;
            int cA = vA ? iA : 0, cB = vB ? iB : 0;

            int hA = cA / Nk, kkA = cA - hA*Nk;  int wA = kbase + kkA;
            int hB = cB / Nk, kkB = cB - hB*Nk;  int wB = kbase + kkB;

            float hfA = (float)(hA - 64), wfA = (float)wA;
            float xiA = M01*hfA + M00*wfA;
            float ziA = M21*hfA + M20*wfA + 64.f;
            float yiA = M11*hfA + M10*wfA + 64.f;
            bool negA = xiA < 0.f;
            if (negA){ xiA = -xiA; ziA = 128.f - ziA; yiA = 128.f - yiA; }
            xiA = fminf(xiA, 65.f);
            ziA = fminf(fmaxf(ziA, -1.f), 129.f);
            yiA = fminf(fmaxf(yiA, -1.f), 129.f);
            float zfA = floorf(ziA), yfA = floorf(yiA), xfA = floorf(xiA);
            float fzA = ziA - zfA, fyA = yiA - yfA, fxA = xiA - xfA;
            int z0A = (int)zfA, y0A = (int)yfA, x0A = (int)xfA;
            int baseiA = ((z0A+1)*PY + (y0A+1))*PX + x0A;

            float hfB = (float)(hB - 64), wfB = (float)wB;
            float xiB = M01*hfB + M00*wfB;
            float ziB = M21*hfB + M20*wfB + 64.f;
            float yiB = M11*hfB + M10*wfB + 64.f;
            bool negB = xiB < 0.f;
            if (negB){ xiB = -xiB; ziB = 128.f - ziB; yiB = 128.f - yiB; }
            xiB = fminf(xiB, 65.f);
            ziB = fminf(fmaxf(ziB, -1.f), 129.f);
            yiB = fminf(fmaxf(yiB, -1.f), 129.f);
            float zfB = floorf(ziB), yfB = floorf(yiB), xfB = floorf(xiB);
            float fzB = ziB - zfB, fyB = yiB - yfB, fxB = xiB - xfB;
            int z0B = (int)zfB, y0B = (int)yfB, x0B = (int)xfB;
            int baseiB = ((z0B+1)*PY + (y0B+1))*PX + x0B;

            // issue all 8 gathers + 2 Fc loads before any consumption
            f4 a00 = *reinterpret_cast<const f4*>(VrP + baseiA);
            f4 a01 = *reinterpret_cast<const f4*>(VrP + baseiA + PROW);
            f4 a10 = *reinterpret_cast<const f4*>(VrP + baseiA + PPLANE);
            f4 a11 = *reinterpret_cast<const f4*>(VrP + baseiA + PPLANE + PROW);
            f4 b00 = *reinterpret_cast<const f4*>(VrP + baseiB);
            f4 b01 = *reinterpret_cast<const f4*>(VrP + baseiB + PROW);
            f4 b10 = *reinterpret_cast<const f4*>(VrP + baseiB + PPLANE);
            f4 b11 = *reinterpret_cast<const f4*>(VrP + baseiB + PPLANE + PROW);
            float2 fA = FcB[hA*KX + wA];
            float2 fB = FcB[hB*KX + wB];

            {
                float gx = 1.f - fxA;
                float r00 = a00.x*gx + a00.z*fxA, i00 = a00.y*gx + a00.w*fxA;
                float r01 = a01.x*gx + a01.z*fxA, i01 = a01.y*gx + a01.w*fxA;
                float r10 = a10.x*gx + a10.z*fxA, i10 = a10.y*gx + a10.w*fxA;
                float r11 = a11.x*gx + a11.z*fxA, i11 = a11.y*gx + a11.w*fxA;
                float gz = 1.f - fzA, gy = 1.f - fyA;
                float w00 = gz*gy, w01 = gz*fyA, w10 = fzA*gy, w11 = fzA*fyA;
                float sr = r00*w00 + r01*w01 + r10*w10 + r11*w11;
                float si = i00*w00 + i01*w01 + i10*w10 + i11*w11;
                if (negA) si = -si;
                if (vA) sP[hA*17 + kkA] = make_float2(fA.x*sr + fA.y*si, fA.y*sr - fA.x*si);
            }
            {
                float gx = 1.f - fxB;
                float r00 = b00.x*gx + b00.z*fxB, i00 = b00.y*gx + b00.w*fxB;
                float r01 = b01.x*gx + b01.z*fxB, i01 = b01.y*gx + b01.w*fxB;
                float r10 = b10.x*gx + b10.z*fxB, i10 = b10.y*gx + b10.w*fxB;
                float r11 = b11.x*gx + b11.z*fxB, i11 = b11.y*gx + b11.w*fxB;
                float gz = 1.f - fzB, gy = 1.f - fyB;
                float w00 = gz*gy, w01 = gz*fyB, w10 = fzB*gy, w11 = fzB*fyB;
                float sr = r00*w00 + r01*w01 + r10*w10 + r11*w11;
                float si = i00*w00 + i01*w01 + i10*w10 + i11*w11;
                if (negB) si = -si;
                if (vB) sP[hB*17 + kkB] = make_float2(fB.x*sr + fB.y*si, fB.y*sr - fB.x*si);
            }
        }
        __syncthreads();

        // Level 1 (inverse: u_c = a + i^c b + (-1)^c c2 + (-i)^c d), rows 32c+n
        for (int i = tid; i < 32*Nk; i += 256){
            int n = i / Nk, kk = i - n*Nk;
            int o0 = n*17 + kk;
            float2 a  = sP[o0];
            float2 bb = sP[o0 + 32*17];
            float2 c2 = sP[o0 + 64*17];
            float2 d  = sP[o0 + 96*17];
            float acx = a.x + c2.x, acy = a.y + c2.y;
            float amx = a.x - c2.x, amy = a.y - c2.y;
            float bdx = bb.x + d.x, bdy = bb.y + d.y;
            float bmx = bb.x - d.x, bmy = bb.y - d.y;
            sP[o0        ] = make_float2(acx + bdx, acy + bdy);   // c=0
            sP[o0 + 32*17] = make_float2(amx - bmy, amy + bmx);   // c=1: + i(b-d)
            sP[o0 + 64*17] = make_float2(acx - bdx, acy - bdy);   // c=2
            sP[o0 + 96*17] = make_float2(amx + bmy, amy - bmx);   // c=3: - i(b-d)
        }
        __syncthreads();

        // Level 2 in place (inverse): v_s[n2] = sum_j u[n2+8j] w^{cj} i^{sj}
        for (int i = tid; i < 32*Nk; i += 256){
            int q = i / Nk, kk = i - q*Nk;
            int c = q >> 3, n2 = q & 7;
            int b0 = (32*c + n2)*17 + kk;
            float2 u0 = sP[b0], u1 = sP[b0+8*17], u2 = sP[b0+16*17], u3 = sP[b0+24*17];
            float2 w1 = sTw[(8*c)&127], w2 = sTw[(16*c)&127], w3 = sTw[(24*c)&127];
            float2 t1 = cmul(u1,w1), t2 = cmul(u2,w2), t3 = cmul(u3,w3);
            float2 p  = make_float2(u0.x+t2.x, u0.y+t2.y);
            float2 qq = make_float2(u0.x-t2.x, u0.y-t2.y);
            float2 r  = make_float2(t1.x+t3.x, t1.y+t3.y);
            float2 s  = make_float2(t1.x-t3.x, t1.y-t3.y);
            sP[b0       ] = make_float2(p.x+r.x,  p.y+r.y);    // s=0
            sP[b0+ 8*17 ] = make_float2(qq.x-s.y, qq.y+s.x);   // s=1: q + i s
            sP[b0+16*17 ] = make_float2(p.x-r.x,  p.y-r.y);    // s=2
            sP[b0+24*17 ] = make_float2(qq.x+s.y, qq.y-s.x);   // s=3: q - i s
        }
        __syncthreads();

        // Phase 2: 8-term y-IDFT per needed row
        for (int o = tid; o < WIN*Nk; o += 256){
            int a = o / Nk, kk = o - a*Nk;
            int ry = (116 + a) & 127;
            int c = ry & 3, s4 = (ry >> 2) & 3;
            const float2* v = &sP[(32*c + 8*s4)*17 + kk];
            float ar0=0,ai0=0,ar1=0,ai1=0;
            int j = 0;
            #pragma unroll
            for (int n2 = 0; n2 < 8; n2 += 2){
                float2 v0 = v[n2*17], v1 = v[(n2+1)*17];
                float2 e0 = sTw[j]; int jn = (j + ry)&127;
                float2 e1 = sTw[jn];
                ar0 += v0.x*e0.x - v0.y*e0.y;  ai0 += v0.x*e0.y + v0.y*e0.x;
                ar1 += v1.x*e1.x - v1.y*e1.y;  ai1 += v1.x*e1.y + v1.y*e1.x;
                j = (jn + ry)&127;
            }
            float sgn = (a & 1) ? -(1.f/128.f) : (1.f/128.f);   // (-1)^ry / 128
            sT[a*KX + kbase + kk] = make_float2((ar0+ar1)*sgn, (ai0+ai1)*sgn);
        }
        __syncthreads();
    }

    // Phase 3a: Hermitian fold into sP (free): Ae (even rx) / Ao (odd rx)
    float2* sPf = sP;
    for (int o = tid; o < WIN*31; o += 256){
        int a = o / 31, km1 = o - a*31;
        int k = km1 + 1;
        const float2* Trow = &sT[a*KX];
        float2 T1 = Trow[k], T2 = Trow[64-k];
        sPf[a*31 + km1]       = make_float2(T1.x + T2.x, T1.y - T2.y);
        sPf[744 + a*31 + km1] = make_float2(T1.x - T2.x, T1.y + T2.y);
    }
    __syncthreads();

    // Phase 3b: 31-term folded x-irfft on the 24x24 window
    float* sC = reinterpret_cast<float*>(sP + 1488);
    for (int o = tid; o < WIN*WIN; o += 256){
        int a = o / WIN, bx = o - a*WIN;
        int rx = (116 + bx) & 127;
        const float2* Trow = &sT[a*KX];
        float2 T32 = Trow[32];
        float base = Trow[0].x + ((bx & 1) ? -Trow[64].x : Trow[64].x);
        int r4 = rx & 3;
        base += (r4==0) ?  2.f*T32.x : (r4==1) ? -2.f*T32.y
              : (r4==2) ? -2.f*T32.x :  2.f*T32.y;
        const float2* A = sPf + ((bx & 1) ? 744 : 0) + a*31 - 1;  // A[k], k=1..31
        float acc0=0.f, acc1=0.f;
        int j1 = rx, j2 = (2*rx)&127;
        int st = (2*rx)&127;
        for (int k = 1; k < 31; k += 2){
            float2 e1 = sTw[j1]; float2 A1v = A[k];
            float2 e2 = sTw[j2]; float2 A2v = A[k+1];
            acc0 += A1v.x*e1.x - A1v.y*e1.y;
            acc1 += A2v.x*e2.x - A2v.y*e2.y;
            j1=(j1+st)&127; j2=(j2+st)&127;
        }
        {
            float2 e = sTw[(31*rx)&127]; float2 Av = A[31];
            acc0 += Av.x*e.x - Av.y*e.y;
        }
        sC[o] = (base + 2.f*(acc0+acc1))*(1.f/128.f);
    }
    __syncthreads();

    // Phase 4: argmax, row-major first occurrence — wave-level shfl_xor reduce
    float best = -FLT_MAX; int bidx = 0x7fffffff;
    for (int i = tid; i < WIN*WIN; i += 256){
        float v = sC[i];
        if (v > best){ best = v; bidx = i; }
    }
    #pragma unroll
    for (int s = 32; s > 0; s >>= 1){
        float ov = __shfl_xor(best, s, 64);
        int   oi = __shfl_xor(bidx, s, 64);
        if (ov > best || (ov == best && oi < bidx)){ best = ov; bidx = oi; }
    }
    if ((tid & 63) == 0){ swv[tid>>6] = best; swi[tid>>6] = bidx; }
    __syncthreads();
    if (tid == 0){
        float bv = swv[0]; int bi = swi[0];
        #pragma unroll
        for (int w2 = 1; w2 < 4; ++w2){
            if (swv[w2] > bv || (swv[w2] == bv && swi[w2] < bi)){ bv = swv[w2]; bi = swi[w2]; }
        }
        int a = bi / WIN, bx = bi - a*WIN;
        resVal[blk] = bv;
        resShift[blk] = make_int2(H0 + bx, H0 + a);
    }
}

// Final: per-batch top-2 (stable ties), mean/std(ddof=1), erf — parallel.
__global__ __launch_bounds__(256) void k_final(const float* __restrict__ resVal,
                        const int2* __restrict__ resShift,
                        const float* __restrict__ grid, float* __restrict__ out)
{
    __shared__ float sv[256];
    __shared__ int   si[256];
    __shared__ float sr[256];
    __shared__ float sMean;
    const int N = NTT*NG;   // 250
    int b = blockIdx.x, tid = threadIdx.x;
    const float* v = resVal + b*N;
    float myv = (tid < N) ? v[tid] : -FLT_MAX;

    sv[tid] = myv; si[tid] = (tid < N) ? tid : 0x7fffffff;
    __syncthreads();
    for (int s = 128; s > 0; s >>= 1){
        if (tid < s){
            float v2 = sv[tid+s]; int i2 = si[tid+s];
            if (v2 > sv[tid] || (v2 == sv[tid] && i2 < si[tid])){ sv[tid]=v2; si[tid]=i2; }
        }
        __syncthreads();
    }
    float v0 = sv[0]; int i0 = si[0];
    __syncthreads();

    bool act = (tid < N) && (tid != i0);
    sv[tid] = act ? myv : -FLT_MAX; si[tid] = act ? tid : 0x7fffffff;
    __syncthreads();
    for (int s = 128; s > 0; s >>= 1){
        if (tid < s){
            float v2 = sv[tid+s]; int i2 = si[tid+s];
            if (v2 > sv[tid] || (v2 == sv[tid] && i2 < si[tid])){ sv[tid]=v2; si[tid]=i2; }
        }
        __syncthreads();
    }
    float v1 = sv[0]; int i1 = si[0];
    __syncthreads();

    sr[tid] = (tid < N) ? myv : 0.f;
    __syncthreads();
    for (int s = 128; s > 0; s >>= 1){
        if (tid < s) sr[tid] += sr[tid+s];
        __syncthreads();
    }
    if (tid == 0) sMean = sr[0] / (float)N;
    __syncthreads();
    float mean = sMean;

    float d = (tid < N) ? (myv - mean) : 0.f;
    sr[tid] = d*d;
    __syncthreads();
    for (int s = 128; s > 0; s >>= 1){
        if (tid < s) sr[tid] += sr[tid+s];
        __syncthreads();
    }

    if (tid == 0){
        float stdv = sqrtf(sr[0] / (float)(N - 1));
        float vals[2] = {v0, v1};
        int   idxs[2] = {i0, i1};
        for (int k = 0; k < 2; ++k){
            out[b*2 + k] = vals[k];
            int gi = idxs[k] % NG;
            for (int j = 0; j < 9; ++j) out[8 + (b*2+k)*9 + j] = grid[gi*9 + j];
            int2 sh = resShift[b*N + idxs[k]];
            out[80 + (b*2+k)*2 + 0] = -((float)sh.x - 64.f)*1.5f;
            out[80 + (b*2+k)*2 + 1] = -((float)sh.y - 64.f)*1.5f;
            out[96 + b*2 + k] = 0.5f*(1.f + erff((vals[k] - mean)/(stdv*1.41421356237309515f)));
        }
    }
}

extern "C" void kernel_launch(void* const* d_in, const int* in_sizes, int n_in,
                              void* d_out, int out_size, void* d_ws, size_t ws_size,
                              hipStream_t stream)
{
    const float* vol  = (const float*)d_in[0];
    const float* imgs = (const float*)d_in[1];
    const float* ctf  = (const float*)d_in[2];
    const float* rotm = (const float*)d_in[3];
    const float* grid = (const float*)d_in[4];
    float* out = (float*)d_out;

    const size_t A1_BYTES  = (size_t)DD*DD*KX*sizeof(float2);   // 8,519,680
    const size_t B1_BYTES  = (size_t)NB*DD*KX*sizeof(float2);   //   266,240
    const size_t VRP_BYTES = (size_t)PZ*PY*PX*sizeof(float2);   // 9,478,656

    char* ws = (char*)d_ws;
    // VrP aliases [A1 | B1 | pad] (dead by the time VrP is written)
    float2* A1  = (float2*)(ws);
    float2* B1  = (float2*)(ws + A1_BYTES);
    float2* VrP = (float2*)(ws);
    size_t off = VRP_BYTES;
    float2* A2 = (float2*)(ws + off); off += A1_BYTES;
    float2* Fc = (float2*)(ws + off); off += B1_BYTES;
    float* resVal = (float*)(ws + off); off += (size_t)NBTG*sizeof(float);
    int2* resShift = (int2*)(ws + off); off += (size_t)NBTG*sizeof(int2);

    k_stageA<<<642, 256, 0, stream>>>(vol, imgs, A1, B1);
    k_stageB<<<642, 256, 0, stream>>>(A1, ctf, B1, A2, Fc);
    k_volD  <<<512, 256, 0, stream>>>(A2, VrP);
    k_main  <<<NBTG,256, 0, stream>>>(VrP, Fc, rotm, grid, resVal, resShift);
    k_final <<<NB,  256, 0, stream>>>(resVal, resShift, grid, out);
}